// Round 7
// baseline (237.632 us; speedup 1.0000x reference)
//
#include <hip/hip_runtime.h>

typedef __fp16 h2 __attribute__((ext_vector_type(2)));       // what cvt_pkrtz returns
typedef _Float16 f16x2 __attribute__((ext_vector_type(2)));  // what fdot2 expects

#define IPB 10        // items per block (250 of 256 lanes active)
#define NT 256
#define NQ 25
#define KVD 9
#define QSCALE 0.4808983469629878f      /* log2(e)/3 : folds 1/sqrt(9) and exp->exp2 */
#define MSCALE (-1.4426950408889634e9f) /* -1e9 * log2(e) */

// v_dot2_f32_f16: 2 f16 MACs per slot, f32 accumulate (2x f32-FMA rate on CDNA)
__device__ __forceinline__ float fdot2(h2 a, h2 b, float c) {
  return __builtin_amdgcn_fdot2(__builtin_bit_cast(f16x2, a),
                                __builtin_bit_cast(f16x2, b), c, false);
}
__device__ __forceinline__ h2 pk(float lo, float hi) {
  return __builtin_amdgcn_cvt_pkrtz(lo, hi);
}

// 9-dim projection in f16-dot2: row = 10 halves (pairs d01,d23,d45,d67,d8+zero),
// padded to 16 halves for b128-aligned rows. 5 fdot2 per output element.
__device__ __forceinline__ void proj9h(const __fp16* __restrict__ w,
                                       const float* __restrict__ bias,
                                       const h2* __restrict__ xh,
                                       float* __restrict__ outv) {
#pragma unroll
  for (int e = 0; e < KVD; ++e) {
    const h2* wr = (const h2*)(w + e * 16);
    float acc = bias[e];
#pragma unroll
    for (int t = 0; t < 5; ++t) acc = fdot2(wr[t], xh[t], acc);
    outv[e] = acc;
  }
}

// NOTE (r6 lesson): the max-shift is REQUIRED here — not for f32 range, but
// because p is packed to f16 for the PV dot2s. max-shift keeps p in (0,1];
// without it exp2(s) overflows f16 (max 65504) and the result is garbage.
__global__ __launch_bounds__(NT, 8) void attn_fused(
    const float* __restrict__ x, const float* __restrict__ mask,
    const float* __restrict__ Wq, const float* __restrict__ bq,
    const float* __restrict__ Wk, const float* __restrict__ bk,
    const float* __restrict__ Wv, const float* __restrict__ bv,
    const float* __restrict__ gamma, const float* __restrict__ beta,
    float* __restrict__ out, int B) {
  __shared__ __align__(16) __fp16 sWh[3][4][KVD][16];  // 3456 B (half9 zeroed, 10..15 unread)
  __shared__ __align__(16) float  sBias[3][4][12];     //  576 B
  __shared__ __align__(16) float  sMsk[28];            //  112 B (mask*MSCALE, score seeds)
  __shared__ __align__(16) __fp16 sKh[IPB][NQ][16];    // 8000 B (K rows, f16, 32B stride)
  __shared__ __align__(16) __fp16 sVT[IPB][KVD][32];   // 5760 B (V transposed, f16, 64B rows)

  const int tid = threadIdx.x;
  const int il = tid / NQ;
  const int tk = tid - il * NQ;
  const long item = (long)blockIdx.x * IPB + il;
  const bool active = (tid < IPB * NQ) && (item < (long)B);

  // ---- prefetch x (f32 kept for residual) ----
  float xv[KVD];
  if (active) {
    const float* xp = x + item * 225 + tk * KVD;
#pragma unroll
    for (int d = 0; d < KVD; ++d) xv[d] = xp[d];
  }

  // ---- stage weights as f16 (Wq pre-scaled by log2e/3), biases f32 ----
  for (int i = tid; i < 324; i += NT) {  // 4*9*9
    int g = i / 81;
    int r = i - g * 81;
    int e = r / 9;
    int d = r - e * 9;
    float a = Wq[i] * QSCALE, b = Wk[i], c = Wv[i];
    if (d == 8) {  // write halves 8,9 as one b32 {w8, 0} -> zero pad deterministic
      *(h2*)&sWh[0][g][e][8] = pk(a, 0.f);
      *(h2*)&sWh[1][g][e][8] = pk(b, 0.f);
      *(h2*)&sWh[2][g][e][8] = pk(c, 0.f);
    } else {
      sWh[0][g][e][d] = (__fp16)a;
      sWh[1][g][e][d] = (__fp16)b;
      sWh[2][g][e][d] = (__fp16)c;
    }
  }
  if (tid < 36) {
    int g = tid / 9, d = tid - g * 9;
    sBias[0][g][d] = bq[tid] * QSCALE;
    sBias[1][g][d] = bk[tid];
    sBias[2][g][d] = bv[tid];
  }
  if (tid < NQ) sMsk[tid] = mask[tid] * MSCALE;
  __syncthreads();

  const int g = (tk < 3) ? 0 : (tk < 13) ? 1 : (tk < 23) ? 2 : 3;
  h2 xh[5];
  if (active) {
    xh[0] = pk(xv[0], xv[1]); xh[1] = pk(xv[2], xv[3]);
    xh[2] = pk(xv[4], xv[5]); xh[3] = pk(xv[6], xv[7]);
    xh[4] = pk(xv[8], 0.f);

    float t[KVD];
    // K projection -> f16 row
    proj9h(&sWh[1][g][0][0], &sBias[1][g][0], xh, t);
    h2* kr = (h2*)&sKh[il][tk][0];
    kr[0] = pk(t[0], t[1]); kr[1] = pk(t[2], t[3]); kr[2] = pk(t[4], t[5]);
    kr[3] = pk(t[6], t[7]); kr[4] = pk(t[8], 0.f);
    // V projection -> transposed f16 (tk==24 also zeroes half 25 via pair store
    // so the PV tail pair never multiplies garbage)
    proj9h(&sWh[2][g][0][0], &sBias[2][g][0], xh, t);
    if (tk == 24) {
#pragma unroll
      for (int d = 0; d < KVD; ++d) *(h2*)&sVT[il][d][24] = pk(t[d], 0.f);
    } else {
#pragma unroll
      for (int d = 0; d < KVD; ++d) sVT[il][d][tk] = (__fp16)t[d];
    }
  }
  __syncthreads();

  if (active) {
    // Q projection after the barrier (short live ranges), then to f16 pairs
    float qf[KVD];
    proj9h(&sWh[0][g][0][0], &sBias[0][g][0], xh, qf);
    h2 qh[5];
    qh[0] = pk(qf[0], qf[1]); qh[1] = pk(qf[2], qf[3]);
    qh[2] = pk(qf[4], qf[5]); qh[3] = pk(qf[6], qf[7]);
    qh[4] = pk(qf[8], 0.f);

    // ---- scores: seed with precomputed mask*MSCALE, 5 fdot2 per key ----
    float s[NQ];
#pragma unroll
    for (int j = 0; j < NQ; ++j) s[j] = sMsk[j];
#pragma unroll
    for (int j = 0; j < NQ; ++j) {
      const h2* krj = (const h2*)&sKh[il][j][0];
      float a = s[j];
#pragma unroll
      for (int t = 0; t < 5; ++t) a = fdot2(krj[t], qh[t], a);
      s[j] = a;
    }

    // ---- max: v_max3-friendly tree, dep depth 3 ----
    float t0 = fmaxf(fmaxf(s[0], s[1]), s[2]);
    float t1 = fmaxf(fmaxf(s[3], s[4]), s[5]);
    float t2 = fmaxf(fmaxf(s[6], s[7]), s[8]);
    float t3 = fmaxf(fmaxf(s[9], s[10]), s[11]);
    float t4 = fmaxf(fmaxf(s[12], s[13]), s[14]);
    float t5 = fmaxf(fmaxf(s[15], s[16]), s[17]);
    float t6 = fmaxf(fmaxf(s[18], s[19]), s[20]);
    float t7 = fmaxf(fmaxf(s[21], s[22]), s[23]);
    float u0 = fmaxf(fmaxf(t0, t1), t2);
    float u1 = fmaxf(fmaxf(t3, t4), t5);
    float u2 = fmaxf(fmaxf(t6, t7), s[24]);
    const float m = fmaxf(fmaxf(u0, u1), u2);

    // ---- exp2 fused straight into f16 pack: p in (0,1], no f32 writeback ----
    h2 ph[13];
#pragma unroll
    for (int t = 0; t < 12; ++t)
      ph[t] = pk(__builtin_amdgcn_exp2f(s[2 * t] - m),
                 __builtin_amdgcn_exp2f(s[2 * t + 1] - m));
    ph[12] = pk(__builtin_amdgcn_exp2f(s[24] - m), 0.f);

    // ---- denominator: sum of the SAME f16 values used in PV (13 dot2 slots) ----
    const h2 one = {(__fp16)1.f, (__fp16)1.f};
    float sum = 0.f;
#pragma unroll
    for (int t = 0; t < 13; ++t) sum = fdot2(ph[t], one, sum);
    const float inv = __builtin_amdgcn_rcpf(sum);

    // ---- PV: dot2 over token pairs against transposed V ----
    float o[KVD];
#pragma unroll
    for (int d = 0; d < KVD; ++d) {
      const h2* vr = (const h2*)&sVT[il][d][0];
      float a = 0.f;
#pragma unroll
      for (int t = 0; t < 13; ++t) a = fdot2(vr[t], ph[t], a);
      o[d] = a;
    }

    // ---- residual + one-pass LayerNorm (inv folded into residual fmaf) ----
    float r[KVD];
    float sm = 0.f, sq = 0.f;
#pragma unroll
    for (int d = 0; d < KVD; ++d) {
      r[d] = fmaf(o[d], inv, xv[d]);
      sm += r[d];
      sq = fmaf(r[d], r[d], sq);
    }
    const float mu = sm * (1.0f / 9.0f);
    float var = fmaf(mu, -mu, sq * (1.0f / 9.0f));
    const float rs = __builtin_amdgcn_rsqf(var + 1e-5f);
    float* op = out + item * 225 + tk * KVD;
    // gamma/beta: wave-uniform s_loads
#pragma unroll
    for (int d = 0; d < KVD; ++d)
      op[d] = fmaf((r[d] - mu) * rs, gamma[d], beta[d]);
  }
}

extern "C" void kernel_launch(void* const* d_in, const int* in_sizes, int n_in,
                              void* d_out, int out_size, void* d_ws, size_t ws_size,
                              hipStream_t stream) {
  const float* x     = (const float*)d_in[0];
  const float* mask  = (const float*)d_in[1];
  const float* Wq    = (const float*)d_in[2];
  const float* bq    = (const float*)d_in[3];
  const float* Wk    = (const float*)d_in[4];
  const float* bk    = (const float*)d_in[5];
  const float* Wv    = (const float*)d_in[6];
  const float* bv    = (const float*)d_in[7];
  const float* gamma = (const float*)d_in[8];
  const float* beta  = (const float*)d_in[9];
  float* out = (float*)d_out;
  const int B = in_sizes[0] / 225;
  const int grid = (B + IPB - 1) / IPB;
  attn_fused<<<grid, NT, 0, stream>>>(x, mask, Wq, bq, Wk, bk, Wv, bv,
                                      gamma, beta, out, B);
}